// Round 9
// baseline (395.801 us; speedup 1.0000x reference)
//
#include <hip/hip_runtime.h>

#define N_NODES   100000
#define N_EDGES   3200000
#define F_INP     128
#define HID       64
#define N_GRAPHS  512
#define N_CLASSES 2
#define BSH       8                        // bucket shift: 256 target nodes per bucket
#define BSZ       256
#define NB        391                      // ceil(N/256) buckets
#define SCAT_BLOCKS 256                    // proven optimum (R7: more blocks -> shorter runs -> slower)
#define CHUNK     (N_EDGES / SCAT_BLOCKS)  // 12500, exact
#define CAP2      8960                     // per-bucket region: mean 8184, sigma 90 -> +8.6 sigma
#define CAPN      80                       // per-node adj slots: mean 32, sigma 5.66 -> +8.5 sigma
#define MM1_ROWS  32
#define XS_LD     132                      // 128 + 4 pad floats -> bank shift 4/row
#define MM1_BLOCKS ((N_NODES + MM1_ROWS - 1) / MM1_ROWS)   // 3125

// bf16 helpers: RTN encode; decode low/high halves of a packed u32
__device__ __forceinline__ unsigned short f2bf(float f) {
    unsigned int u = __float_as_uint(f);
    return (unsigned short)((u + 0x7FFFu + ((u >> 16) & 1u)) >> 16);
}
__device__ __forceinline__ float bf_lo(unsigned int u) { return __uint_as_float(u << 16); }
__device__ __forceinline__ float bf_hi(unsigned int u) { return __uint_as_float(u & 0xFFFF0000u); }

// ---------- pass 1 (mega-fused): blocks [0,256) scatter edges; blocks [256,3381) do x@W1 ----------
__global__ __launch_bounds__(256) void fused_pre(const int* __restrict__ ei,
                                                 int* __restrict__ gcur,
                                                 int* __restrict__ pairs,
                                                 const float* __restrict__ x,
                                                 const float* __restrict__ W1,
                                                 float* __restrict__ praw) {
    __shared__ __align__(16) char smem[(MM1_ROWS * XS_LD + F_INP * HID) * 4];  // 49.7 KB union
    const int tid = threadIdx.x;
    if (blockIdx.x < SCAT_BLOCKS) {
        // ---- scatter part ----
        int* lcnt = (int*)smem;
        int* lbase = lcnt + NB;
        int* lcur = lbase + NB;
        for (int i = tid; i < NB; i += 256) { lcnt[i] = 0; lcur[i] = 0; }
        __syncthreads();
        const int e0 = blockIdx.x * CHUNK;
        for (int e = e0 + tid; e < e0 + CHUNK; e += 256)
            atomicAdd(&lcnt[ei[N_EDGES + e] >> BSH], 1);
        __syncthreads();
        for (int i = tid; i < NB; i += 256) {
            int c = lcnt[i];
            lbase[i] = c ? atomicAdd(&gcur[i], c) : 0;   // reserve disjoint range
        }
        __syncthreads();
        for (int e = e0 + tid; e < e0 + CHUNK; e += 256) {
            int c = ei[N_EDGES + e];
            int r = ei[e];
            int b = c >> BSH;
            int off = atomicAdd(&lcur[b], 1);
            int pos = lbase[b] + off;
            if (pos < CAP2)                               // ~8.6-sigma guard
                pairs[b * CAP2 + pos] = r | ((c & (BSZ - 1)) << 17);
        }
    } else {
        // ---- mm1 part: praw = x @ W1 (f32, unscaled) ----
        float* xs = (float*)smem;
        float* ws = xs + MM1_ROWS * XS_LD;
        for (int i = tid; i < F_INP * HID / 4; i += 256)
            ((float4*)ws)[i] = ((const float4*)W1)[i];
        const int row_base = (blockIdx.x - SCAT_BLOCKS) * MM1_ROWS;
        for (int i = tid; i < MM1_ROWS * (F_INP / 4); i += 256) {
            int r = i >> 5, c4 = i & 31;
            int gr = row_base + r;
            float4 v = make_float4(0.f, 0.f, 0.f, 0.f);
            if (gr < N_NODES) v = *(const float4*)(x + (size_t)gr * F_INP + c4 * 4);
            *(float4*)(xs + r * XS_LD + c4 * 4) = v;
        }
        __syncthreads();
        const int tx = tid & 15;
        const int ty = tid >> 4;
        float acc[2][4] = {};
#pragma unroll 4
        for (int k = 0; k < F_INP; k += 4) {
            float4 a0 = *(const float4*)(xs + ty * XS_LD + k);
            float4 a1 = *(const float4*)(xs + (ty + 16) * XS_LD + k);
            float4 w0 = *(const float4*)(ws + (k + 0) * HID + tx * 4);
            float4 w1 = *(const float4*)(ws + (k + 1) * HID + tx * 4);
            float4 w2 = *(const float4*)(ws + (k + 2) * HID + tx * 4);
            float4 w3 = *(const float4*)(ws + (k + 3) * HID + tx * 4);
            acc[0][0] += a0.x * w0.x + a0.y * w1.x + a0.z * w2.x + a0.w * w3.x;
            acc[0][1] += a0.x * w0.y + a0.y * w1.y + a0.z * w2.y + a0.w * w3.y;
            acc[0][2] += a0.x * w0.z + a0.y * w1.z + a0.z * w2.z + a0.w * w3.z;
            acc[0][3] += a0.x * w0.w + a0.y * w1.w + a0.z * w2.w + a0.w * w3.w;
            acc[1][0] += a1.x * w0.x + a1.y * w1.x + a1.z * w2.x + a1.w * w3.x;
            acc[1][1] += a1.x * w0.y + a1.y * w1.y + a1.z * w2.y + a1.w * w3.y;
            acc[1][2] += a1.x * w0.z + a1.y * w1.z + a1.z * w2.z + a1.w * w3.z;
            acc[1][3] += a1.x * w0.w + a1.y * w1.w + a1.z * w2.w + a1.w * w3.w;
        }
#pragma unroll
        for (int i = 0; i < 2; ++i) {
            int rr = row_base + ty + 16 * i;
            if (rr < N_NODES)
                *(float4*)(praw + (size_t)rr * HID + tx * 4) =
                    make_float4(acc[i][0], acc[i][1], acc[i][2], acc[i][3]);
        }
    }
}

// ---------- pass 2: single-pass node-padded placement + deg/dis + dis-scale praw->p ----------
// No count pass, no scans, no staging: adj[n*CAPN + rank], rank from LDS atomic.
__global__ __launch_bounds__(512) void placeX(const int* __restrict__ pairs,
                                              const int* __restrict__ gcur,
                                              const float* __restrict__ praw,
                                              unsigned short* __restrict__ p,
                                              int* __restrict__ adj,
                                              int* __restrict__ deg,
                                              float* __restrict__ dis) {
    __shared__ int cur[BSZ];
    const int tid = threadIdx.x;
    const int b = blockIdx.x;
    const int m = min(gcur[b], CAP2);
    if (tid < BSZ) cur[tid] = 0;
    __syncthreads();
    const size_t abase = (size_t)(b << BSH) * CAPN;
    for (int i = tid; i < m; i += 512) {
        int v = pairs[b * CAP2 + i];
        int lc = v >> 17;
        int o = atomicAdd(&cur[lc], 1);
        if (o < CAPN)                                  // ~8.5-sigma guard
            adj[abase + (size_t)lc * CAPN + o] = v & 131071;
    }
    __syncthreads();
    const int n = (b << BSH) + tid;
    if (tid < BSZ && n < N_NODES) {
        deg[n] = min(cur[tid], CAPN);
        dis[n] = rsqrtf((float)cur[tid] + 1.0f);       // +1 = self-loop
    }
    // --- dis-scale this bucket's praw rows (f32) into p (bf16), single rounding ---
    const int nrows = min(BSZ, N_NODES - (b << BSH));
    const float2* pr = (const float2*)(praw + ((size_t)(b << BSH)) * HID);
    unsigned int* p32 = (unsigned int*)(p + ((size_t)(b << BSH)) * HID);
    for (int i = tid; i < nrows * 32; i += 512) {
        int row = i >> 5;
        float d = rsqrtf((float)cur[row] + 1.0f);
        float2 w = pr[i];
        p32[i] = (unsigned int)f2bf(w.x * d) | ((unsigned int)f2bf(w.y * d) << 16);
    }
}

// ---------- round-8 gather core (empirical optimum): 32/16/masked-8 loops ----------
// lane L: q = L>>3 (row slot), g = L&7 (feature octet, feats 8g..8g+7)
__device__ __forceinline__ float gather_node(const unsigned short* __restrict__ p,
                                             const int* __restrict__ adj,
                                             int c, int beg, int end, int q, int g) {
    float acc[8];
    {   // self-loop row, counted once via q==0 lanes
        uint4 s = *(const uint4*)(p + (size_t)c * HID + g * 8);
        float sm = (q == 0) ? 1.f : 0.f;
        acc[0] = sm * bf_lo(s.x); acc[1] = sm * bf_hi(s.x);
        acc[2] = sm * bf_lo(s.y); acc[3] = sm * bf_hi(s.y);
        acc[4] = sm * bf_lo(s.z); acc[5] = sm * bf_hi(s.z);
        acc[6] = sm * bf_lo(s.w); acc[7] = sm * bf_hi(s.w);
    }
    int e = beg;
    for (; e + 32 <= end; e += 32) {            // 4 row-loads in flight
        int r0 = adj[e + q];
        int r1 = adj[e + 8 + q];
        int r2 = adj[e + 16 + q];
        int r3 = adj[e + 24 + q];
        uint4 v0 = *(const uint4*)(p + (size_t)r0 * HID + g * 8);
        uint4 v1 = *(const uint4*)(p + (size_t)r1 * HID + g * 8);
        uint4 v2 = *(const uint4*)(p + (size_t)r2 * HID + g * 8);
        uint4 v3 = *(const uint4*)(p + (size_t)r3 * HID + g * 8);
        acc[0] += (bf_lo(v0.x) + bf_lo(v1.x)) + (bf_lo(v2.x) + bf_lo(v3.x));
        acc[1] += (bf_hi(v0.x) + bf_hi(v1.x)) + (bf_hi(v2.x) + bf_hi(v3.x));
        acc[2] += (bf_lo(v0.y) + bf_lo(v1.y)) + (bf_lo(v2.y) + bf_lo(v3.y));
        acc[3] += (bf_hi(v0.y) + bf_hi(v1.y)) + (bf_hi(v2.y) + bf_hi(v3.y));
        acc[4] += (bf_lo(v0.z) + bf_lo(v1.z)) + (bf_lo(v2.z) + bf_lo(v3.z));
        acc[5] += (bf_hi(v0.z) + bf_hi(v1.z)) + (bf_hi(v2.z) + bf_hi(v3.z));
        acc[6] += (bf_lo(v0.w) + bf_lo(v1.w)) + (bf_lo(v2.w) + bf_lo(v3.w));
        acc[7] += (bf_hi(v0.w) + bf_hi(v1.w)) + (bf_hi(v2.w) + bf_hi(v3.w));
    }
    for (; e + 16 <= end; e += 16) {
        int r0 = adj[e + q];
        int r1 = adj[e + 8 + q];
        uint4 v0 = *(const uint4*)(p + (size_t)r0 * HID + g * 8);
        uint4 v1 = *(const uint4*)(p + (size_t)r1 * HID + g * 8);
        acc[0] += bf_lo(v0.x) + bf_lo(v1.x); acc[1] += bf_hi(v0.x) + bf_hi(v1.x);
        acc[2] += bf_lo(v0.y) + bf_lo(v1.y); acc[3] += bf_hi(v0.y) + bf_hi(v1.y);
        acc[4] += bf_lo(v0.z) + bf_lo(v1.z); acc[5] += bf_hi(v0.z) + bf_hi(v1.z);
        acc[6] += bf_lo(v0.w) + bf_lo(v1.w); acc[7] += bf_hi(v0.w) + bf_hi(v1.w);
    }
    for (; e < end; e += 8) {                   // masked tail
        int idx = e + q;
        int r = adj[min(idx, end - 1)];
        float m = (idx < end) ? 1.f : 0.f;
        uint4 v = *(const uint4*)(p + (size_t)r * HID + g * 8);
        acc[0] = fmaf(m, bf_lo(v.x), acc[0]); acc[1] = fmaf(m, bf_hi(v.x), acc[1]);
        acc[2] = fmaf(m, bf_lo(v.y), acc[2]); acc[3] = fmaf(m, bf_hi(v.y), acc[3]);
        acc[4] = fmaf(m, bf_lo(v.z), acc[4]); acc[5] = fmaf(m, bf_hi(v.z), acc[5]);
        acc[6] = fmaf(m, bf_lo(v.w), acc[6]); acc[7] = fmaf(m, bf_hi(v.w), acc[7]);
    }
    // select-tree reduction over q bits (lane ends with feature 8g+q)
    const bool q0 = (q & 1) != 0, q1 = (q & 2) != 0, q2 = (q & 4) != 0;
    float b0 = (q0 ? acc[1] : acc[0]) + __shfl_xor(q0 ? acc[0] : acc[1], 8, 64);
    float b1 = (q0 ? acc[3] : acc[2]) + __shfl_xor(q0 ? acc[2] : acc[3], 8, 64);
    float b2 = (q0 ? acc[5] : acc[4]) + __shfl_xor(q0 ? acc[4] : acc[5], 8, 64);
    float b3 = (q0 ? acc[7] : acc[6]) + __shfl_xor(q0 ? acc[6] : acc[7], 8, 64);
    float c0 = (q1 ? b1 : b0) + __shfl_xor(q1 ? b0 : b1, 16, 64);
    float c1 = (q1 ? b3 : b2) + __shfl_xor(q1 ? b2 : b3, 16, 64);
    return (q2 ? c1 : c0) + __shfl_xor(q2 ? c0 : c1, 32, 64);
}

// ---------- gather1 + fused mm2: p2 = bf16(dis * (relu(dis*(p[c]+sum)+b1) @ W2)) ----------
// h stays in f32 registers (one per lane, feature (g*8+q)); in-wave 64x64 matmul via
// shfl-broadcast + LDS W2; eliminates the mm2 kernel and the hb round-trip.
__global__ __launch_bounds__(256) void gather1_kernel(const unsigned short* __restrict__ p,
                                                      const int* __restrict__ adj,
                                                      const int* __restrict__ deg,
                                                      const float* __restrict__ dis,
                                                      const float* __restrict__ b1,
                                                      const float* __restrict__ W2,
                                                      unsigned short* __restrict__ p2) {
    __shared__ float w2s[HID * HID];   // 16 KB, [f][j]
    for (int i = threadIdx.x; i < HID * HID / 4; i += 256)
        ((float4*)w2s)[i] = ((const float4*)W2)[i];
    __syncthreads();
    const int lane = threadIdx.x & 63;
    const int q = lane >> 3, g = lane & 7;
    const int gwave = (blockIdx.x * blockDim.x + threadIdx.x) >> 6;
    const int nwaves = (gridDim.x * blockDim.x) >> 6;
    const int per = (N_NODES + nwaves - 1) / nwaves;
    const int c0 = gwave * per;
    const int c1 = min(N_NODES, c0 + per);
    const float bj = b1[g * 8 + q];
    for (int c = c0; c < c1; ++c) {
        const int beg = c * CAPN;
        const int end = beg + deg[c];
        float val = gather_node(p, adj, c, beg, end, q, g);
        const float dc = dis[c];
        float h = fmaxf(dc * val + bj, 0.f);          // f32 h, feature g*8+q
        // in-wave h @ W2: lane j accumulates output feature j; 4 chains for ILP
        float a0 = 0.f, a1 = 0.f, a2 = 0.f, a3 = 0.f;
#pragma unroll 8
        for (int f = 0; f < HID; f += 4) {
            float h0 = __shfl(h, (((f + 0) & 7) << 3) | ((f + 0) >> 3), 64);
            float h1 = __shfl(h, (((f + 1) & 7) << 3) | ((f + 1) >> 3), 64);
            float h2 = __shfl(h, (((f + 2) & 7) << 3) | ((f + 2) >> 3), 64);
            float h3 = __shfl(h, (((f + 3) & 7) << 3) | ((f + 3) >> 3), 64);
            a0 = fmaf(h0, w2s[(f + 0) * HID + lane], a0);
            a1 = fmaf(h1, w2s[(f + 1) * HID + lane], a1);
            a2 = fmaf(h2, w2s[(f + 2) * HID + lane], a2);
            a3 = fmaf(h3, w2s[(f + 3) * HID + lane], a3);
        }
        p2[(size_t)c * HID + lane] = f2bf(dc * ((a0 + a1) + (a2 + a3)));
    }
}

// ---------- gather2 + mean-pool numerator (run-length atomics over sorted batch) ----------
__global__ __launch_bounds__(256) void gather2_kernel(const unsigned short* __restrict__ p,
                                                      const int* __restrict__ adj,
                                                      const int* __restrict__ deg,
                                                      const float* __restrict__ dis,
                                                      const float* __restrict__ b2,
                                                      const int* __restrict__ batch,
                                                      float* __restrict__ sums) {
    const int lane = threadIdx.x & 63;
    const int q = lane >> 3, g = lane & 7;
    const int gwave = (blockIdx.x * blockDim.x + threadIdx.x) >> 6;
    const int nwaves = (gridDim.x * blockDim.x) >> 6;
    const int per = (N_NODES + nwaves - 1) / nwaves;
    const int c0 = gwave * per;
    const int c1 = min(N_NODES, c0 + per);
    const float bj = b2[g * 8 + q];
    const int feat = g * 8 + q;
    float part = 0.f;
    int gc = -1;
    for (int c = c0; c < c1; ++c) {
        const int beg = c * CAPN;
        const int end = beg + deg[c];
        float val = gather_node(p, adj, c, beg, end, q, g);
        float v = fmaxf(dis[c] * val + bj, 0.f);
        int gid = batch[c];                       // wave-uniform
        if (gid != gc) {
            if (gc >= 0) atomicAdd(&sums[(size_t)gc * HID + feat], part);
            part = 0.f;
            gc = gid;
        }
        part += v;
    }
    if (gc >= 0) atomicAdd(&sums[(size_t)gc * HID + feat], part);
}

// ---------- final FC (counts fused via binary search on sorted batch) ----------
__global__ void fc_kernel(const float* __restrict__ sums, const int* __restrict__ batch,
                          const float* __restrict__ Wfc, const float* __restrict__ bfc,
                          float* __restrict__ out) {
    const int g = blockIdx.x;
    const int j = threadIdx.x;
    int lo = 0, hi = N_NODES;
    while (lo < hi) { int m = (lo + hi) >> 1; if (batch[m] < g) lo = m + 1; else hi = m; }
    const int l0 = lo;
    lo = 0; hi = N_NODES;
    while (lo < hi) { int m = (lo + hi) >> 1; if (batch[m] < g + 1) lo = m + 1; else hi = m; }
    float cnt = fmaxf((float)(lo - l0), 1.0f);
    float pj = sums[(size_t)g * HID + j] / cnt;
    float a0 = pj * Wfc[j * N_CLASSES + 0];
    float a1 = pj * Wfc[j * N_CLASSES + 1];
    for (int off = 32; off > 0; off >>= 1) {
        a0 += __shfl_down(a0, off, 64);
        a1 += __shfl_down(a1, off, 64);
    }
    if (j == 0) {
        out[g * N_CLASSES + 0] = a0 + bfc[0];
        out[g * N_CLASSES + 1] = a1 + bfc[1];
    }
}

extern "C" void kernel_launch(void* const* d_in, const int* in_sizes, int n_in,
                              void* d_out, int out_size, void* d_ws, size_t ws_size,
                              hipStream_t stream) {
    const float* x     = (const float*)d_in[0];
    const int*   ei    = (const int*)d_in[1];   // [2,E]: row=ei[0:E], col=ei[E:2E]
    const int*   batch = (const int*)d_in[2];
    const float* W1    = (const float*)d_in[3];
    const float* b1    = (const float*)d_in[4];
    const float* W2    = (const float*)d_in[5];
    const float* b2    = (const float*)d_in[6];
    const float* Wfc   = (const float*)d_in[7];
    const float* bfc   = (const float*)d_in[8];
    float* out = (float*)d_out;

    char* ws = (char*)d_ws;
    size_t off = 0;
    auto alloc = [&](size_t bytes) -> void* {
        void* pp = ws + off;
        off += (bytes + 255) & ~(size_t)255;
        return pp;
    };
    // gcur and sums adjacent -> single memset covers both
    int*   gcur   = (int*)alloc((size_t)NB * 4);                      // 1.6 KB
    float* sums   = (float*)alloc((size_t)N_GRAPHS * HID * 4);        // 128 KB
    int*   deg    = (int*)alloc((size_t)N_NODES * 4);
    float* dis    = (float*)alloc((size_t)N_NODES * 4);
    int*   pairs  = (int*)alloc((size_t)NB * CAP2 * 4);               // 14.0 MB
    int*   adj    = (int*)alloc((size_t)N_NODES * CAPN * 4);          // 32.0 MB node-padded
    float* praw   = (float*)alloc((size_t)N_NODES * HID * 4);         // 25.6 MB f32
    unsigned short* p  = (unsigned short*)alloc((size_t)N_NODES * HID * 2);
    unsigned short* p2 = (unsigned short*)alloc((size_t)N_NODES * HID * 2);

    hipMemsetAsync(gcur, 0, (size_t)((char*)(sums + N_GRAPHS * HID) - (char*)gcur), stream);

    fused_pre<<<SCAT_BLOCKS + MM1_BLOCKS, 256, 0, stream>>>(ei, gcur, pairs, x, W1, praw);
    placeX<<<NB, 512, 0, stream>>>(pairs, gcur, praw, p, adj, deg, dis);
    gather1_kernel<<<2048, 256, 0, stream>>>(p, adj, deg, dis, b1, W2, p2);
    gather2_kernel<<<2048, 256, 0, stream>>>(p2, adj, deg, dis, b2, batch, sums);
    fc_kernel<<<N_GRAPHS, 64, 0, stream>>>(sums, batch, Wfc, bfc, out);
}

// Round 10
// 352.849 us; speedup vs baseline: 1.1217x; 1.1217x over previous
//
#include <hip/hip_runtime.h>

#define N_NODES   100000
#define N_EDGES   3200000
#define F_INP     128
#define HID       64
#define N_GRAPHS  512
#define N_CLASSES 2
#define BSH       8                        // bucket shift: 256 target nodes per bucket
#define BSZ       256
#define NB        391                      // ceil(N/256) buckets
#define SCAT_BLOCKS 256                    // proven optimum (R7: more blocks -> shorter runs -> slower)
#define CHUNK     (N_EDGES / SCAT_BLOCKS)  // 12500, exact
#define CAP2      8960                     // per-bucket region: mean 8184, sigma 90 -> +8.6 sigma
#define CAPN      80                       // per-node adj slots: mean 32, sigma 5.66 -> +8.5 sigma
#define MM1_ROWS  32
#define XS_LD     132                      // 128 + 4 pad floats -> bank shift 4/row
#define MM1_BLOCKS ((N_NODES + MM1_ROWS - 1) / MM1_ROWS)   // 3125

// bf16 helpers: RTN encode; decode low/high halves of a packed u32
__device__ __forceinline__ unsigned short f2bf(float f) {
    unsigned int u = __float_as_uint(f);
    return (unsigned short)((u + 0x7FFFu + ((u >> 16) & 1u)) >> 16);
}
__device__ __forceinline__ float bf_lo(unsigned int u) { return __uint_as_float(u << 16); }
__device__ __forceinline__ float bf_hi(unsigned int u) { return __uint_as_float(u & 0xFFFF0000u); }

// ---------- pass 1 (mega-fused): blocks [0,256) scatter edges; blocks [256,3381) do x@W1 ----------
__global__ __launch_bounds__(256) void fused_pre(const int* __restrict__ ei,
                                                 int* __restrict__ gcur,
                                                 int* __restrict__ pairs,
                                                 const float* __restrict__ x,
                                                 const float* __restrict__ W1,
                                                 float* __restrict__ praw) {
    __shared__ __align__(16) char smem[(MM1_ROWS * XS_LD + F_INP * HID) * 4];  // 49.7 KB union
    const int tid = threadIdx.x;
    if (blockIdx.x < SCAT_BLOCKS) {
        // ---- scatter part ----
        int* lcnt = (int*)smem;
        int* lbase = lcnt + NB;
        int* lcur = lbase + NB;
        for (int i = tid; i < NB; i += 256) { lcnt[i] = 0; lcur[i] = 0; }
        __syncthreads();
        const int e0 = blockIdx.x * CHUNK;
        for (int e = e0 + tid; e < e0 + CHUNK; e += 256)
            atomicAdd(&lcnt[ei[N_EDGES + e] >> BSH], 1);
        __syncthreads();
        for (int i = tid; i < NB; i += 256) {
            int c = lcnt[i];
            lbase[i] = c ? atomicAdd(&gcur[i], c) : 0;   // reserve disjoint range
        }
        __syncthreads();
        for (int e = e0 + tid; e < e0 + CHUNK; e += 256) {
            int c = ei[N_EDGES + e];
            int r = ei[e];
            int b = c >> BSH;
            int off = atomicAdd(&lcur[b], 1);
            int pos = lbase[b] + off;
            if (pos < CAP2)                               // ~8.6-sigma guard
                pairs[b * CAP2 + pos] = r | ((c & (BSZ - 1)) << 17);
        }
    } else {
        // ---- mm1 part: praw = x @ W1 (f32, unscaled) ----
        float* xs = (float*)smem;
        float* ws = xs + MM1_ROWS * XS_LD;
        for (int i = tid; i < F_INP * HID / 4; i += 256)
            ((float4*)ws)[i] = ((const float4*)W1)[i];
        const int row_base = (blockIdx.x - SCAT_BLOCKS) * MM1_ROWS;
        for (int i = tid; i < MM1_ROWS * (F_INP / 4); i += 256) {
            int r = i >> 5, c4 = i & 31;
            int gr = row_base + r;
            float4 v = make_float4(0.f, 0.f, 0.f, 0.f);
            if (gr < N_NODES) v = *(const float4*)(x + (size_t)gr * F_INP + c4 * 4);
            *(float4*)(xs + r * XS_LD + c4 * 4) = v;
        }
        __syncthreads();
        const int tx = tid & 15;
        const int ty = tid >> 4;
        float acc[2][4] = {};
#pragma unroll 4
        for (int k = 0; k < F_INP; k += 4) {
            float4 a0 = *(const float4*)(xs + ty * XS_LD + k);
            float4 a1 = *(const float4*)(xs + (ty + 16) * XS_LD + k);
            float4 w0 = *(const float4*)(ws + (k + 0) * HID + tx * 4);
            float4 w1 = *(const float4*)(ws + (k + 1) * HID + tx * 4);
            float4 w2 = *(const float4*)(ws + (k + 2) * HID + tx * 4);
            float4 w3 = *(const float4*)(ws + (k + 3) * HID + tx * 4);
            acc[0][0] += a0.x * w0.x + a0.y * w1.x + a0.z * w2.x + a0.w * w3.x;
            acc[0][1] += a0.x * w0.y + a0.y * w1.y + a0.z * w2.y + a0.w * w3.y;
            acc[0][2] += a0.x * w0.z + a0.y * w1.z + a0.z * w2.z + a0.w * w3.z;
            acc[0][3] += a0.x * w0.w + a0.y * w1.w + a0.z * w2.w + a0.w * w3.w;
            acc[1][0] += a1.x * w0.x + a1.y * w1.x + a1.z * w2.x + a1.w * w3.x;
            acc[1][1] += a1.x * w0.y + a1.y * w1.y + a1.z * w2.y + a1.w * w3.y;
            acc[1][2] += a1.x * w0.z + a1.y * w1.z + a1.z * w2.z + a1.w * w3.z;
            acc[1][3] += a1.x * w0.w + a1.y * w1.w + a1.z * w2.w + a1.w * w3.w;
        }
#pragma unroll
        for (int i = 0; i < 2; ++i) {
            int rr = row_base + ty + 16 * i;
            if (rr < N_NODES)
                *(float4*)(praw + (size_t)rr * HID + tx * 4) =
                    make_float4(acc[i][0], acc[i][1], acc[i][2], acc[i][3]);
        }
    }
}

// ---------- pass 2: single-pass node-padded placement + deg/dis + dis-scale praw->p ----------
__global__ __launch_bounds__(512) void placeX(const int* __restrict__ pairs,
                                              const int* __restrict__ gcur,
                                              const float* __restrict__ praw,
                                              unsigned short* __restrict__ p,
                                              int* __restrict__ adj,
                                              int* __restrict__ deg,
                                              float* __restrict__ dis) {
    __shared__ int cur[BSZ];
    const int tid = threadIdx.x;
    const int b = blockIdx.x;
    const int m = min(gcur[b], CAP2);
    if (tid < BSZ) cur[tid] = 0;
    __syncthreads();
    const size_t abase = (size_t)(b << BSH) * CAPN;
    for (int i = tid; i < m; i += 512) {
        int v = pairs[b * CAP2 + i];
        int lc = v >> 17;
        int o = atomicAdd(&cur[lc], 1);
        if (o < CAPN)                                  // ~8.5-sigma guard
            adj[abase + (size_t)lc * CAPN + o] = v & 131071;
    }
    __syncthreads();
    const int n = (b << BSH) + tid;
    if (tid < BSZ && n < N_NODES) {
        deg[n] = min(cur[tid], CAPN);
        dis[n] = rsqrtf((float)cur[tid] + 1.0f);       // +1 = self-loop
    }
    // --- dis-scale this bucket's praw rows (f32) into p (bf16), single rounding ---
    const int nrows = min(BSZ, N_NODES - (b << BSH));
    const float2* pr = (const float2*)(praw + ((size_t)(b << BSH)) * HID);
    unsigned int* p32 = (unsigned int*)(p + ((size_t)(b << BSH)) * HID);
    for (int i = tid; i < nrows * 32; i += 512) {
        int row = i >> 5;
        float d = rsqrtf((float)cur[row] + 1.0f);
        float2 w = pr[i];
        p32[i] = (unsigned int)f2bf(w.x * d) | ((unsigned int)f2bf(w.y * d) << 16);
    }
}

// ---------- round-8 gather core (empirical optimum): 32/16/masked-8 loops ----------
// lane L: q = L>>3 (row slot), g = L&7 (feature octet, feats 8g..8g+7)
__device__ __forceinline__ float gather_node(const unsigned short* __restrict__ p,
                                             const int* __restrict__ adj,
                                             int c, int beg, int end, int q, int g) {
    float acc[8];
    {   // self-loop row, counted once via q==0 lanes
        uint4 s = *(const uint4*)(p + (size_t)c * HID + g * 8);
        float sm = (q == 0) ? 1.f : 0.f;
        acc[0] = sm * bf_lo(s.x); acc[1] = sm * bf_hi(s.x);
        acc[2] = sm * bf_lo(s.y); acc[3] = sm * bf_hi(s.y);
        acc[4] = sm * bf_lo(s.z); acc[5] = sm * bf_hi(s.z);
        acc[6] = sm * bf_lo(s.w); acc[7] = sm * bf_hi(s.w);
    }
    int e = beg;
    for (; e + 32 <= end; e += 32) {            // 4 row-loads in flight
        int r0 = adj[e + q];
        int r1 = adj[e + 8 + q];
        int r2 = adj[e + 16 + q];
        int r3 = adj[e + 24 + q];
        uint4 v0 = *(const uint4*)(p + (size_t)r0 * HID + g * 8);
        uint4 v1 = *(const uint4*)(p + (size_t)r1 * HID + g * 8);
        uint4 v2 = *(const uint4*)(p + (size_t)r2 * HID + g * 8);
        uint4 v3 = *(const uint4*)(p + (size_t)r3 * HID + g * 8);
        acc[0] += (bf_lo(v0.x) + bf_lo(v1.x)) + (bf_lo(v2.x) + bf_lo(v3.x));
        acc[1] += (bf_hi(v0.x) + bf_hi(v1.x)) + (bf_hi(v2.x) + bf_hi(v3.x));
        acc[2] += (bf_lo(v0.y) + bf_lo(v1.y)) + (bf_lo(v2.y) + bf_lo(v3.y));
        acc[3] += (bf_hi(v0.y) + bf_hi(v1.y)) + (bf_hi(v2.y) + bf_hi(v3.y));
        acc[4] += (bf_lo(v0.z) + bf_lo(v1.z)) + (bf_lo(v2.z) + bf_lo(v3.z));
        acc[5] += (bf_hi(v0.z) + bf_hi(v1.z)) + (bf_hi(v2.z) + bf_hi(v3.z));
        acc[6] += (bf_lo(v0.w) + bf_lo(v1.w)) + (bf_lo(v2.w) + bf_lo(v3.w));
        acc[7] += (bf_hi(v0.w) + bf_hi(v1.w)) + (bf_hi(v2.w) + bf_hi(v3.w));
    }
    for (; e + 16 <= end; e += 16) {
        int r0 = adj[e + q];
        int r1 = adj[e + 8 + q];
        uint4 v0 = *(const uint4*)(p + (size_t)r0 * HID + g * 8);
        uint4 v1 = *(const uint4*)(p + (size_t)r1 * HID + g * 8);
        acc[0] += bf_lo(v0.x) + bf_lo(v1.x); acc[1] += bf_hi(v0.x) + bf_hi(v1.x);
        acc[2] += bf_lo(v0.y) + bf_lo(v1.y); acc[3] += bf_hi(v0.y) + bf_hi(v1.y);
        acc[4] += bf_lo(v0.z) + bf_lo(v1.z); acc[5] += bf_hi(v0.z) + bf_hi(v1.z);
        acc[6] += bf_lo(v0.w) + bf_lo(v1.w); acc[7] += bf_hi(v0.w) + bf_hi(v1.w);
    }
    for (; e < end; e += 8) {                   // masked tail
        int idx = e + q;
        int r = adj[min(idx, end - 1)];
        float m = (idx < end) ? 1.f : 0.f;
        uint4 v = *(const uint4*)(p + (size_t)r * HID + g * 8);
        acc[0] = fmaf(m, bf_lo(v.x), acc[0]); acc[1] = fmaf(m, bf_hi(v.x), acc[1]);
        acc[2] = fmaf(m, bf_lo(v.y), acc[2]); acc[3] = fmaf(m, bf_hi(v.y), acc[3]);
        acc[4] = fmaf(m, bf_lo(v.z), acc[4]); acc[5] = fmaf(m, bf_hi(v.z), acc[5]);
        acc[6] = fmaf(m, bf_lo(v.w), acc[6]); acc[7] = fmaf(m, bf_hi(v.w), acc[7]);
    }
    // select-tree reduction over q bits (lane ends with feature 8g+q)
    const bool q0 = (q & 1) != 0, q1 = (q & 2) != 0, q2 = (q & 4) != 0;
    float b0 = (q0 ? acc[1] : acc[0]) + __shfl_xor(q0 ? acc[0] : acc[1], 8, 64);
    float b1 = (q0 ? acc[3] : acc[2]) + __shfl_xor(q0 ? acc[2] : acc[3], 8, 64);
    float b2 = (q0 ? acc[5] : acc[4]) + __shfl_xor(q0 ? acc[4] : acc[5], 8, 64);
    float b3 = (q0 ? acc[7] : acc[6]) + __shfl_xor(q0 ? acc[6] : acc[7], 8, 64);
    float c0 = (q1 ? b1 : b0) + __shfl_xor(q1 ? b0 : b1, 16, 64);
    float c1 = (q1 ? b3 : b2) + __shfl_xor(q1 ? b2 : b3, 16, 64);
    return (q2 ? c1 : c0) + __shfl_xor(q2 ? c0 : c1, 32, 64);
}

// ---------- gather1: hb = bf16(relu(dis[c]*(p[c]+sum p[r]) + b1)) ----------
__global__ __launch_bounds__(256) void gather1_kernel(const unsigned short* __restrict__ p,
                                                      const int* __restrict__ adj,
                                                      const int* __restrict__ deg,
                                                      const float* __restrict__ dis,
                                                      const float* __restrict__ b1,
                                                      unsigned short* __restrict__ hb) {
    const int lane = threadIdx.x & 63;
    const int q = lane >> 3, g = lane & 7;
    const int gwave = (blockIdx.x * blockDim.x + threadIdx.x) >> 6;
    const int nwaves = (gridDim.x * blockDim.x) >> 6;
    const int per = (N_NODES + nwaves - 1) / nwaves;
    const int c0 = gwave * per;
    const int c1 = min(N_NODES, c0 + per);
    const float bj = b1[g * 8 + q];
    for (int c = c0; c < c1; ++c) {
        const int beg = c * CAPN;
        const int end = beg + deg[c];
        float val = gather_node(p, adj, c, beg, end, q, g);
        hb[(size_t)c * HID + g * 8 + q] = f2bf(fmaxf(dis[c] * val + bj, 0.f));
    }
}

// ---------- mm2: p = bf16(dis * (h @ W2)), 64-row bf16 tile, padded ----------
#define HS_LD 72                            // 64 + 8 pad bf16 -> 144 B/row, bank shift 4
__global__ __launch_bounds__(256) void mm2_kernel(const unsigned short* __restrict__ hb,
                                                  const float* __restrict__ W2,
                                                  const float* __restrict__ dis,
                                                  unsigned short* __restrict__ p) {
    __shared__ unsigned short hs[64 * HS_LD];  // 9.2 KB
    __shared__ float ws[HID * HID];            // 16 KB
    for (int i = threadIdx.x; i < HID * HID / 4; i += 256)
        ((float4*)ws)[i] = ((const float4*)W2)[i];
    const int row_base = blockIdx.x * 64;
    for (int i = threadIdx.x; i < 64 * (HID / 8); i += 256) {
        int r = i >> 3, c8 = i & 7;
        int gr = row_base + r;
        uint4 v = make_uint4(0u, 0u, 0u, 0u);
        if (gr < N_NODES) v = *(const uint4*)(hb + (size_t)gr * HID + c8 * 8);
        *(uint4*)(hs + r * HS_LD + c8 * 8) = v;
    }
    __syncthreads();
    const int tx = threadIdx.x & 15;
    const int ty = threadIdx.x >> 4;
    float acc[4][4] = {};
#pragma unroll 2
    for (int k = 0; k < HID; k += 8) {
        uint4 a[4];
#pragma unroll
        for (int i = 0; i < 4; ++i)
            a[i] = *(const uint4*)(hs + (ty + 16 * i) * HS_LD + k);
        float4 w[8];
#pragma unroll
        for (int m = 0; m < 8; ++m)
            w[m] = *(const float4*)(ws + (k + m) * HID + tx * 4);
#pragma unroll
        for (int i = 0; i < 4; ++i) {
            float h0 = bf_lo(a[i].x), h1 = bf_hi(a[i].x);
            float h2 = bf_lo(a[i].y), h3 = bf_hi(a[i].y);
            float h4 = bf_lo(a[i].z), h5 = bf_hi(a[i].z);
            float h6 = bf_lo(a[i].w), h7 = bf_hi(a[i].w);
            acc[i][0] += h0 * w[0].x + h1 * w[1].x + h2 * w[2].x + h3 * w[3].x
                       + h4 * w[4].x + h5 * w[5].x + h6 * w[6].x + h7 * w[7].x;
            acc[i][1] += h0 * w[0].y + h1 * w[1].y + h2 * w[2].y + h3 * w[3].y
                       + h4 * w[4].y + h5 * w[5].y + h6 * w[6].y + h7 * w[7].y;
            acc[i][2] += h0 * w[0].z + h1 * w[1].z + h2 * w[2].z + h3 * w[3].z
                       + h4 * w[4].z + h5 * w[5].z + h6 * w[6].z + h7 * w[7].z;
            acc[i][3] += h0 * w[0].w + h1 * w[1].w + h2 * w[2].w + h3 * w[3].w
                       + h4 * w[4].w + h5 * w[5].w + h6 * w[6].w + h7 * w[7].w;
        }
    }
#pragma unroll
    for (int i = 0; i < 4; ++i) {
        int rr = row_base + ty + 16 * i;
        if (rr < N_NODES) {
            float d = dis[rr];
            ushort4 o;
            o.x = f2bf(d * acc[i][0]);
            o.y = f2bf(d * acc[i][1]);
            o.z = f2bf(d * acc[i][2]);
            o.w = f2bf(d * acc[i][3]);
            *(ushort4*)(p + (size_t)rr * HID + tx * 4) = o;
        }
    }
}

// ---------- gather2 + mean-pool numerator (run-length atomics over sorted batch) ----------
__global__ __launch_bounds__(256) void gather2_kernel(const unsigned short* __restrict__ p,
                                                      const int* __restrict__ adj,
                                                      const int* __restrict__ deg,
                                                      const float* __restrict__ dis,
                                                      const float* __restrict__ b2,
                                                      const int* __restrict__ batch,
                                                      float* __restrict__ sums) {
    const int lane = threadIdx.x & 63;
    const int q = lane >> 3, g = lane & 7;
    const int gwave = (blockIdx.x * blockDim.x + threadIdx.x) >> 6;
    const int nwaves = (gridDim.x * blockDim.x) >> 6;
    const int per = (N_NODES + nwaves - 1) / nwaves;
    const int c0 = gwave * per;
    const int c1 = min(N_NODES, c0 + per);
    const float bj = b2[g * 8 + q];
    const int feat = g * 8 + q;
    float part = 0.f;
    int gc = -1;
    for (int c = c0; c < c1; ++c) {
        const int beg = c * CAPN;
        const int end = beg + deg[c];
        float val = gather_node(p, adj, c, beg, end, q, g);
        float v = fmaxf(dis[c] * val + bj, 0.f);
        int gid = batch[c];                       // wave-uniform
        if (gid != gc) {
            if (gc >= 0) atomicAdd(&sums[(size_t)gc * HID + feat], part);
            part = 0.f;
            gc = gid;
        }
        part += v;
    }
    if (gc >= 0) atomicAdd(&sums[(size_t)gc * HID + feat], part);
}

// ---------- final FC (counts fused via binary search on sorted batch) ----------
__global__ void fc_kernel(const float* __restrict__ sums, const int* __restrict__ batch,
                          const float* __restrict__ Wfc, const float* __restrict__ bfc,
                          float* __restrict__ out) {
    const int g = blockIdx.x;
    const int j = threadIdx.x;
    int lo = 0, hi = N_NODES;
    while (lo < hi) { int m = (lo + hi) >> 1; if (batch[m] < g) lo = m + 1; else hi = m; }
    const int l0 = lo;
    lo = 0; hi = N_NODES;
    while (lo < hi) { int m = (lo + hi) >> 1; if (batch[m] < g + 1) lo = m + 1; else hi = m; }
    float cnt = fmaxf((float)(lo - l0), 1.0f);
    float pj = sums[(size_t)g * HID + j] / cnt;
    float a0 = pj * Wfc[j * N_CLASSES + 0];
    float a1 = pj * Wfc[j * N_CLASSES + 1];
    for (int off = 32; off > 0; off >>= 1) {
        a0 += __shfl_down(a0, off, 64);
        a1 += __shfl_down(a1, off, 64);
    }
    if (j == 0) {
        out[g * N_CLASSES + 0] = a0 + bfc[0];
        out[g * N_CLASSES + 1] = a1 + bfc[1];
    }
}

extern "C" void kernel_launch(void* const* d_in, const int* in_sizes, int n_in,
                              void* d_out, int out_size, void* d_ws, size_t ws_size,
                              hipStream_t stream) {
    const float* x     = (const float*)d_in[0];
    const int*   ei    = (const int*)d_in[1];   // [2,E]: row=ei[0:E], col=ei[E:2E]
    const int*   batch = (const int*)d_in[2];
    const float* W1    = (const float*)d_in[3];
    const float* b1    = (const float*)d_in[4];
    const float* W2    = (const float*)d_in[5];
    const float* b2    = (const float*)d_in[6];
    const float* Wfc   = (const float*)d_in[7];
    const float* bfc   = (const float*)d_in[8];
    float* out = (float*)d_out;

    char* ws = (char*)d_ws;
    size_t off = 0;
    auto alloc = [&](size_t bytes) -> void* {
        void* pp = ws + off;
        off += (bytes + 255) & ~(size_t)255;
        return pp;
    };
    // gcur and sums adjacent -> single memset covers both
    int*   gcur   = (int*)alloc((size_t)NB * 4);                      // 1.6 KB
    float* sums   = (float*)alloc((size_t)N_GRAPHS * HID * 4);        // 128 KB
    int*   deg    = (int*)alloc((size_t)N_NODES * 4);
    float* dis    = (float*)alloc((size_t)N_NODES * 4);
    int*   pairs  = (int*)alloc((size_t)NB * CAP2 * 4);               // 14.0 MB
    int*   adj    = (int*)alloc((size_t)N_NODES * CAPN * 4);          // 32.0 MB node-padded
    float* praw   = (float*)alloc((size_t)N_NODES * HID * 4);         // 25.6 MB f32
    unsigned short* p  = (unsigned short*)alloc((size_t)N_NODES * HID * 2);
    unsigned short* hb = (unsigned short*)alloc((size_t)N_NODES * HID * 2);

    hipMemsetAsync(gcur, 0, (size_t)((char*)(sums + N_GRAPHS * HID) - (char*)gcur), stream);

    fused_pre<<<SCAT_BLOCKS + MM1_BLOCKS, 256, 0, stream>>>(ei, gcur, pairs, x, W1, praw);
    placeX<<<NB, 512, 0, stream>>>(pairs, gcur, praw, p, adj, deg, dis);
    gather1_kernel<<<2048, 256, 0, stream>>>(p, adj, deg, dis, b1, hb);
    mm2_kernel<<<(N_NODES + 63) / 64, 256, 0, stream>>>(hb, W2, dis, p);
    gather2_kernel<<<2048, 256, 0, stream>>>(p, adj, deg, dis, b2, batch, sums);
    fc_kernel<<<N_GRAPHS, 64, 0, stream>>>(sums, batch, Wfc, bfc, out);
}

// Round 11
// 351.239 us; speedup vs baseline: 1.1269x; 1.0046x over previous
//
#include <hip/hip_runtime.h>

#define N_NODES   100000
#define N_EDGES   3200000
#define F_INP     128
#define HID       64
#define N_GRAPHS  512
#define N_CLASSES 2
#define BSH       7                        // bucket shift: 128 target nodes per bucket
#define BSZ       128
#define NB        782                      // ceil(N/128) buckets
#define SCAT_BLOCKS 256                    // proven optimum (R7: more blocks -> shorter runs -> slower)
#define CHUNK     (N_EDGES / SCAT_BLOCKS)  // 12500, exact
#define CAP2      4608                     // per-bucket region: mean 4092, sigma 64 -> +8 sigma
#define CAPN      80                       // per-node adj slots: mean 32, sigma 5.66 -> +8.5 sigma
#define MM1_ROWS  32
#define XS_LD     132                      // 128 + 4 pad floats -> bank shift 4/row
#define MM1_BLOCKS ((N_NODES + MM1_ROWS - 1) / MM1_ROWS)   // 3125

// bf16 helpers: RTN encode; decode low/high halves of a packed u32
__device__ __forceinline__ unsigned short f2bf(float f) {
    unsigned int u = __float_as_uint(f);
    return (unsigned short)((u + 0x7FFFu + ((u >> 16) & 1u)) >> 16);
}
__device__ __forceinline__ float bf_lo(unsigned int u) { return __uint_as_float(u << 16); }
__device__ __forceinline__ float bf_hi(unsigned int u) { return __uint_as_float(u & 0xFFFF0000u); }

// ---------- pass 1 (mega-fused): blocks [0,256) scatter edges; blocks [256,3381) do x@W1 ----------
__global__ __launch_bounds__(256) void fused_pre(const int* __restrict__ ei,
                                                 int* __restrict__ gcur,
                                                 int* __restrict__ pairs,
                                                 const float* __restrict__ x,
                                                 const float* __restrict__ W1,
                                                 float* __restrict__ praw) {
    __shared__ __align__(16) char smem[(MM1_ROWS * XS_LD + F_INP * HID) * 4];  // 49.7 KB union
    const int tid = threadIdx.x;
    if (blockIdx.x < SCAT_BLOCKS) {
        // ---- scatter part ----
        int* lcnt = (int*)smem;
        int* lbase = lcnt + NB;
        int* lcur = lbase + NB;
        for (int i = tid; i < NB; i += 256) { lcnt[i] = 0; lcur[i] = 0; }
        __syncthreads();
        const int e0 = blockIdx.x * CHUNK;
        for (int e = e0 + tid; e < e0 + CHUNK; e += 256)
            atomicAdd(&lcnt[ei[N_EDGES + e] >> BSH], 1);
        __syncthreads();
        for (int i = tid; i < NB; i += 256) {
            int c = lcnt[i];
            lbase[i] = c ? atomicAdd(&gcur[i], c) : 0;   // reserve disjoint range
        }
        __syncthreads();
        for (int e = e0 + tid; e < e0 + CHUNK; e += 256) {
            int c = ei[N_EDGES + e];
            int r = ei[e];
            int b = c >> BSH;
            int off = atomicAdd(&lcur[b], 1);
            int pos = lbase[b] + off;
            if (pos < CAP2)                               // ~8-sigma guard
                pairs[b * CAP2 + pos] = r | ((c & (BSZ - 1)) << 17);
        }
    } else {
        // ---- mm1 part: praw = x @ W1 (f32, unscaled) ----
        float* xs = (float*)smem;
        float* ws = xs + MM1_ROWS * XS_LD;
        for (int i = tid; i < F_INP * HID / 4; i += 256)
            ((float4*)ws)[i] = ((const float4*)W1)[i];
        const int row_base = (blockIdx.x - SCAT_BLOCKS) * MM1_ROWS;
        for (int i = tid; i < MM1_ROWS * (F_INP / 4); i += 256) {
            int r = i >> 5, c4 = i & 31;
            int gr = row_base + r;
            float4 v = make_float4(0.f, 0.f, 0.f, 0.f);
            if (gr < N_NODES) v = *(const float4*)(x + (size_t)gr * F_INP + c4 * 4);
            *(float4*)(xs + r * XS_LD + c4 * 4) = v;
        }
        __syncthreads();
        const int tx = tid & 15;
        const int ty = tid >> 4;
        float acc[2][4] = {};
#pragma unroll 4
        for (int k = 0; k < F_INP; k += 4) {
            float4 a0 = *(const float4*)(xs + ty * XS_LD + k);
            float4 a1 = *(const float4*)(xs + (ty + 16) * XS_LD + k);
            float4 w0 = *(const float4*)(ws + (k + 0) * HID + tx * 4);
            float4 w1 = *(const float4*)(ws + (k + 1) * HID + tx * 4);
            float4 w2 = *(const float4*)(ws + (k + 2) * HID + tx * 4);
            float4 w3 = *(const float4*)(ws + (k + 3) * HID + tx * 4);
            acc[0][0] += a0.x * w0.x + a0.y * w1.x + a0.z * w2.x + a0.w * w3.x;
            acc[0][1] += a0.x * w0.y + a0.y * w1.y + a0.z * w2.y + a0.w * w3.y;
            acc[0][2] += a0.x * w0.z + a0.y * w1.z + a0.z * w2.z + a0.w * w3.z;
            acc[0][3] += a0.x * w0.w + a0.y * w1.w + a0.z * w2.w + a0.w * w3.w;
            acc[1][0] += a1.x * w0.x + a1.y * w1.x + a1.z * w2.x + a1.w * w3.x;
            acc[1][1] += a1.x * w0.y + a1.y * w1.y + a1.z * w2.y + a1.w * w3.y;
            acc[1][2] += a1.x * w0.z + a1.y * w1.z + a1.z * w2.z + a1.w * w3.z;
            acc[1][3] += a1.x * w0.w + a1.y * w1.w + a1.z * w2.w + a1.w * w3.w;
        }
#pragma unroll
        for (int i = 0; i < 2; ++i) {
            int rr = row_base + ty + 16 * i;
            if (rr < N_NODES)
                *(float4*)(praw + (size_t)rr * HID + tx * 4) =
                    make_float4(acc[i][0], acc[i][1], acc[i][2], acc[i][3]);
        }
    }
}

// ---------- pass 2: single-pass placement, LDS-staged adj (write-combined out) ----------
// Place into LDS sadj[128][80] via LDS-atomic rank (one E-pass), then stream the whole
// region out linearly (full-line coalesced stores; garbage slots harmless, gather reads [0,deg)).
__global__ __launch_bounds__(512) void placeX(const int* __restrict__ pairs,
                                              const int* __restrict__ gcur,
                                              const float* __restrict__ praw,
                                              unsigned short* __restrict__ p,
                                              int* __restrict__ adj,
                                              int* __restrict__ deg,
                                              float* __restrict__ dis) {
    __shared__ int sadj[BSZ * CAPN];   // 40 KB staging
    __shared__ int cur[BSZ];
    const int tid = threadIdx.x;
    const int b = blockIdx.x;
    const int m = min(gcur[b], CAP2);
    if (tid < BSZ) cur[tid] = 0;
    __syncthreads();
    for (int i = tid; i < m; i += 512) {
        int v = pairs[b * CAP2 + i];
        int lc = v >> 17;
        int o = atomicAdd(&cur[lc], 1);
        if (o < CAPN)                                  // ~8.5-sigma guard
            sadj[lc * CAPN + o] = v & 131071;
    }
    __syncthreads();
    const int nrows = min(BSZ, N_NODES - (b << BSH));
    // coalesced copy-out: int4 over nrows*CAPN ints (CAPN%4==0)
    int4* adj4 = (int4*)(adj + (size_t)(b << BSH) * CAPN);
    const int4* sadj4 = (const int4*)sadj;
    for (int i = tid; i < (nrows * CAPN) >> 2; i += 512)
        adj4[i] = sadj4[i];
    const int n = (b << BSH) + tid;
    if (tid < BSZ && n < N_NODES) {
        deg[n] = min(cur[tid], CAPN);
        dis[n] = rsqrtf((float)cur[tid] + 1.0f);       // +1 = self-loop
    }
    // --- dis-scale this bucket's praw rows (f32) into p (bf16), single rounding ---
    const float2* pr = (const float2*)(praw + ((size_t)(b << BSH)) * HID);
    unsigned int* p32 = (unsigned int*)(p + ((size_t)(b << BSH)) * HID);
    for (int i = tid; i < nrows * 32; i += 512) {
        int row = i >> 5;
        float d = rsqrtf((float)cur[row] + 1.0f);
        float2 w = pr[i];
        p32[i] = (unsigned int)f2bf(w.x * d) | ((unsigned int)f2bf(w.y * d) << 16);
    }
}

// ---------- round-8 gather core (empirical optimum): 32/16/masked-8 loops ----------
// lane L: q = L>>3 (row slot), g = L&7 (feature octet, feats 8g..8g+7)
__device__ __forceinline__ float gather_node(const unsigned short* __restrict__ p,
                                             const int* __restrict__ adj,
                                             int c, int beg, int end, int q, int g) {
    float acc[8];
    {   // self-loop row, counted once via q==0 lanes
        uint4 s = *(const uint4*)(p + (size_t)c * HID + g * 8);
        float sm = (q == 0) ? 1.f : 0.f;
        acc[0] = sm * bf_lo(s.x); acc[1] = sm * bf_hi(s.x);
        acc[2] = sm * bf_lo(s.y); acc[3] = sm * bf_hi(s.y);
        acc[4] = sm * bf_lo(s.z); acc[5] = sm * bf_hi(s.z);
        acc[6] = sm * bf_lo(s.w); acc[7] = sm * bf_hi(s.w);
    }
    int e = beg;
    for (; e + 32 <= end; e += 32) {            // 4 row-loads in flight
        int r0 = adj[e + q];
        int r1 = adj[e + 8 + q];
        int r2 = adj[e + 16 + q];
        int r3 = adj[e + 24 + q];
        uint4 v0 = *(const uint4*)(p + (size_t)r0 * HID + g * 8);
        uint4 v1 = *(const uint4*)(p + (size_t)r1 * HID + g * 8);
        uint4 v2 = *(const uint4*)(p + (size_t)r2 * HID + g * 8);
        uint4 v3 = *(const uint4*)(p + (size_t)r3 * HID + g * 8);
        acc[0] += (bf_lo(v0.x) + bf_lo(v1.x)) + (bf_lo(v2.x) + bf_lo(v3.x));
        acc[1] += (bf_hi(v0.x) + bf_hi(v1.x)) + (bf_hi(v2.x) + bf_hi(v3.x));
        acc[2] += (bf_lo(v0.y) + bf_lo(v1.y)) + (bf_lo(v2.y) + bf_lo(v3.y));
        acc[3] += (bf_hi(v0.y) + bf_hi(v1.y)) + (bf_hi(v2.y) + bf_hi(v3.y));
        acc[4] += (bf_lo(v0.z) + bf_lo(v1.z)) + (bf_lo(v2.z) + bf_lo(v3.z));
        acc[5] += (bf_hi(v0.z) + bf_hi(v1.z)) + (bf_hi(v2.z) + bf_hi(v3.z));
        acc[6] += (bf_lo(v0.w) + bf_lo(v1.w)) + (bf_lo(v2.w) + bf_lo(v3.w));
        acc[7] += (bf_hi(v0.w) + bf_hi(v1.w)) + (bf_hi(v2.w) + bf_hi(v3.w));
    }
    for (; e + 16 <= end; e += 16) {
        int r0 = adj[e + q];
        int r1 = adj[e + 8 + q];
        uint4 v0 = *(const uint4*)(p + (size_t)r0 * HID + g * 8);
        uint4 v1 = *(const uint4*)(p + (size_t)r1 * HID + g * 8);
        acc[0] += bf_lo(v0.x) + bf_lo(v1.x); acc[1] += bf_hi(v0.x) + bf_hi(v1.x);
        acc[2] += bf_lo(v0.y) + bf_lo(v1.y); acc[3] += bf_hi(v0.y) + bf_hi(v1.y);
        acc[4] += bf_lo(v0.z) + bf_lo(v1.z); acc[5] += bf_hi(v0.z) + bf_hi(v1.z);
        acc[6] += bf_lo(v0.w) + bf_lo(v1.w); acc[7] += bf_hi(v0.w) + bf_hi(v1.w);
    }
    for (; e < end; e += 8) {                   // masked tail
        int idx = e + q;
        int r = adj[min(idx, end - 1)];
        float m = (idx < end) ? 1.f : 0.f;
        uint4 v = *(const uint4*)(p + (size_t)r * HID + g * 8);
        acc[0] = fmaf(m, bf_lo(v.x), acc[0]); acc[1] = fmaf(m, bf_hi(v.x), acc[1]);
        acc[2] = fmaf(m, bf_lo(v.y), acc[2]); acc[3] = fmaf(m, bf_hi(v.y), acc[3]);
        acc[4] = fmaf(m, bf_lo(v.z), acc[4]); acc[5] = fmaf(m, bf_hi(v.z), acc[5]);
        acc[6] = fmaf(m, bf_lo(v.w), acc[6]); acc[7] = fmaf(m, bf_hi(v.w), acc[7]);
    }
    // select-tree reduction over q bits (lane ends with feature 8g+q)
    const bool q0 = (q & 1) != 0, q1 = (q & 2) != 0, q2 = (q & 4) != 0;
    float b0 = (q0 ? acc[1] : acc[0]) + __shfl_xor(q0 ? acc[0] : acc[1], 8, 64);
    float b1 = (q0 ? acc[3] : acc[2]) + __shfl_xor(q0 ? acc[2] : acc[3], 8, 64);
    float b2 = (q0 ? acc[5] : acc[4]) + __shfl_xor(q0 ? acc[4] : acc[5], 8, 64);
    float b3 = (q0 ? acc[7] : acc[6]) + __shfl_xor(q0 ? acc[6] : acc[7], 8, 64);
    float c0 = (q1 ? b1 : b0) + __shfl_xor(q1 ? b0 : b1, 16, 64);
    float c1 = (q1 ? b3 : b2) + __shfl_xor(q1 ? b2 : b3, 16, 64);
    return (q2 ? c1 : c0) + __shfl_xor(q2 ? c0 : c1, 32, 64);
}

// ---------- gather1: hb = bf16(relu(dis[c]*(p[c]+sum p[r]) + b1)) ----------
__global__ __launch_bounds__(256) void gather1_kernel(const unsigned short* __restrict__ p,
                                                      const int* __restrict__ adj,
                                                      const int* __restrict__ deg,
                                                      const float* __restrict__ dis,
                                                      const float* __restrict__ b1,
                                                      unsigned short* __restrict__ hb) {
    const int lane = threadIdx.x & 63;
    const int q = lane >> 3, g = lane & 7;
    const int gwave = (blockIdx.x * blockDim.x + threadIdx.x) >> 6;
    const int nwaves = (gridDim.x * blockDim.x) >> 6;
    const int per = (N_NODES + nwaves - 1) / nwaves;
    const int c0 = gwave * per;
    const int c1 = min(N_NODES, c0 + per);
    const float bj = b1[g * 8 + q];
    for (int c = c0; c < c1; ++c) {
        const int beg = c * CAPN;
        const int end = beg + deg[c];
        float val = gather_node(p, adj, c, beg, end, q, g);
        hb[(size_t)c * HID + g * 8 + q] = f2bf(fmaxf(dis[c] * val + bj, 0.f));
    }
}

// ---------- mm2: p = bf16(dis * (h @ W2)), 64-row bf16 tile, padded ----------
#define HS_LD 72                            // 64 + 8 pad bf16 -> 144 B/row, bank shift 4
__global__ __launch_bounds__(256) void mm2_kernel(const unsigned short* __restrict__ hb,
                                                  const float* __restrict__ W2,
                                                  const float* __restrict__ dis,
                                                  unsigned short* __restrict__ p) {
    __shared__ unsigned short hs[64 * HS_LD];  // 9.2 KB
    __shared__ float ws[HID * HID];            // 16 KB
    for (int i = threadIdx.x; i < HID * HID / 4; i += 256)
        ((float4*)ws)[i] = ((const float4*)W2)[i];
    const int row_base = blockIdx.x * 64;
    for (int i = threadIdx.x; i < 64 * (HID / 8); i += 256) {
        int r = i >> 3, c8 = i & 7;
        int gr = row_base + r;
        uint4 v = make_uint4(0u, 0u, 0u, 0u);
        if (gr < N_NODES) v = *(const uint4*)(hb + (size_t)gr * HID + c8 * 8);
        *(uint4*)(hs + r * HS_LD + c8 * 8) = v;
    }
    __syncthreads();
    const int tx = threadIdx.x & 15;
    const int ty = threadIdx.x >> 4;
    float acc[4][4] = {};
#pragma unroll 2
    for (int k = 0; k < HID; k += 8) {
        uint4 a[4];
#pragma unroll
        for (int i = 0; i < 4; ++i)
            a[i] = *(const uint4*)(hs + (ty + 16 * i) * HS_LD + k);
        float4 w[8];
#pragma unroll
        for (int m = 0; m < 8; ++m)
            w[m] = *(const float4*)(ws + (k + m) * HID + tx * 4);
#pragma unroll
        for (int i = 0; i < 4; ++i) {
            float h0 = bf_lo(a[i].x), h1 = bf_hi(a[i].x);
            float h2 = bf_lo(a[i].y), h3 = bf_hi(a[i].y);
            float h4 = bf_lo(a[i].z), h5 = bf_hi(a[i].z);
            float h6 = bf_lo(a[i].w), h7 = bf_hi(a[i].w);
            acc[i][0] += h0 * w[0].x + h1 * w[1].x + h2 * w[2].x + h3 * w[3].x
                       + h4 * w[4].x + h5 * w[5].x + h6 * w[6].x + h7 * w[7].x;
            acc[i][1] += h0 * w[0].y + h1 * w[1].y + h2 * w[2].y + h3 * w[3].y
                       + h4 * w[4].y + h5 * w[5].y + h6 * w[6].y + h7 * w[7].y;
            acc[i][2] += h0 * w[0].z + h1 * w[1].z + h2 * w[2].z + h3 * w[3].z
                       + h4 * w[4].z + h5 * w[5].z + h6 * w[6].z + h7 * w[7].z;
            acc[i][3] += h0 * w[0].w + h1 * w[1].w + h2 * w[2].w + h3 * w[3].w
                       + h4 * w[4].w + h5 * w[5].w + h6 * w[6].w + h7 * w[7].w;
        }
    }
#pragma unroll
    for (int i = 0; i < 4; ++i) {
        int rr = row_base + ty + 16 * i;
        if (rr < N_NODES) {
            float d = dis[rr];
            ushort4 o;
            o.x = f2bf(d * acc[i][0]);
            o.y = f2bf(d * acc[i][1]);
            o.z = f2bf(d * acc[i][2]);
            o.w = f2bf(d * acc[i][3]);
            *(ushort4*)(p + (size_t)rr * HID + tx * 4) = o;
        }
    }
}

// ---------- gather2 + mean-pool numerator (run-length atomics over sorted batch) ----------
__global__ __launch_bounds__(256) void gather2_kernel(const unsigned short* __restrict__ p,
                                                      const int* __restrict__ adj,
                                                      const int* __restrict__ deg,
                                                      const float* __restrict__ dis,
                                                      const float* __restrict__ b2,
                                                      const int* __restrict__ batch,
                                                      float* __restrict__ sums) {
    const int lane = threadIdx.x & 63;
    const int q = lane >> 3, g = lane & 7;
    const int gwave = (blockIdx.x * blockDim.x + threadIdx.x) >> 6;
    const int nwaves = (gridDim.x * blockDim.x) >> 6;
    const int per = (N_NODES + nwaves - 1) / nwaves;
    const int c0 = gwave * per;
    const int c1 = min(N_NODES, c0 + per);
    const float bj = b2[g * 8 + q];
    const int feat = g * 8 + q;
    float part = 0.f;
    int gc = -1;
    for (int c = c0; c < c1; ++c) {
        const int beg = c * CAPN;
        const int end = beg + deg[c];
        float val = gather_node(p, adj, c, beg, end, q, g);
        float v = fmaxf(dis[c] * val + bj, 0.f);
        int gid = batch[c];                       // wave-uniform
        if (gid != gc) {
            if (gc >= 0) atomicAdd(&sums[(size_t)gc * HID + feat], part);
            part = 0.f;
            gc = gid;
        }
        part += v;
    }
    if (gc >= 0) atomicAdd(&sums[(size_t)gc * HID + feat], part);
}

// ---------- final FC (counts fused via binary search on sorted batch) ----------
__global__ void fc_kernel(const float* __restrict__ sums, const int* __restrict__ batch,
                          const float* __restrict__ Wfc, const float* __restrict__ bfc,
                          float* __restrict__ out) {
    const int g = blockIdx.x;
    const int j = threadIdx.x;
    int lo = 0, hi = N_NODES;
    while (lo < hi) { int m = (lo + hi) >> 1; if (batch[m] < g) lo = m + 1; else hi = m; }
    const int l0 = lo;
    lo = 0; hi = N_NODES;
    while (lo < hi) { int m = (lo + hi) >> 1; if (batch[m] < g + 1) lo = m + 1; else hi = m; }
    float cnt = fmaxf((float)(lo - l0), 1.0f);
    float pj = sums[(size_t)g * HID + j] / cnt;
    float a0 = pj * Wfc[j * N_CLASSES + 0];
    float a1 = pj * Wfc[j * N_CLASSES + 1];
    for (int off = 32; off > 0; off >>= 1) {
        a0 += __shfl_down(a0, off, 64);
        a1 += __shfl_down(a1, off, 64);
    }
    if (j == 0) {
        out[g * N_CLASSES + 0] = a0 + bfc[0];
        out[g * N_CLASSES + 1] = a1 + bfc[1];
    }
}

extern "C" void kernel_launch(void* const* d_in, const int* in_sizes, int n_in,
                              void* d_out, int out_size, void* d_ws, size_t ws_size,
                              hipStream_t stream) {
    const float* x     = (const float*)d_in[0];
    const int*   ei    = (const int*)d_in[1];   // [2,E]: row=ei[0:E], col=ei[E:2E]
    const int*   batch = (const int*)d_in[2];
    const float* W1    = (const float*)d_in[3];
    const float* b1    = (const float*)d_in[4];
    const float* W2    = (const float*)d_in[5];
    const float* b2    = (const float*)d_in[6];
    const float* Wfc   = (const float*)d_in[7];
    const float* bfc   = (const float*)d_in[8];
    float* out = (float*)d_out;

    char* ws = (char*)d_ws;
    size_t off = 0;
    auto alloc = [&](size_t bytes) -> void* {
        void* pp = ws + off;
        off += (bytes + 255) & ~(size_t)255;
        return pp;
    };
    // gcur and sums adjacent -> single memset covers both
    int*   gcur   = (int*)alloc((size_t)NB * 4);                      // 3.1 KB
    float* sums   = (float*)alloc((size_t)N_GRAPHS * HID * 4);        // 128 KB
    int*   deg    = (int*)alloc((size_t)N_NODES * 4);
    float* dis    = (float*)alloc((size_t)N_NODES * 4);
    int*   pairs  = (int*)alloc((size_t)NB * CAP2 * 4);               // 14.4 MB
    int*   adj    = (int*)alloc((size_t)N_NODES * CAPN * 4);          // 32.0 MB node-padded
    float* praw   = (float*)alloc((size_t)N_NODES * HID * 4);         // 25.6 MB f32
    unsigned short* p  = (unsigned short*)alloc((size_t)N_NODES * HID * 2);
    unsigned short* hb = (unsigned short*)alloc((size_t)N_NODES * HID * 2);

    hipMemsetAsync(gcur, 0, (size_t)((char*)(sums + N_GRAPHS * HID) - (char*)gcur), stream);

    fused_pre<<<SCAT_BLOCKS + MM1_BLOCKS, 256, 0, stream>>>(ei, gcur, pairs, x, W1, praw);
    placeX<<<NB, 512, 0, stream>>>(pairs, gcur, praw, p, adj, deg, dis);
    gather1_kernel<<<2048, 256, 0, stream>>>(p, adj, deg, dis, b1, hb);
    mm2_kernel<<<(N_NODES + 63) / 64, 256, 0, stream>>>(hb, W2, dis, p);
    gather2_kernel<<<2048, 256, 0, stream>>>(p, adj, deg, dis, b2, batch, sums);
    fc_kernel<<<N_GRAPHS, 64, 0, stream>>>(sums, batch, Wfc, bfc, out);
}